// Round 12
// baseline (152.250 us; speedup 1.0000x reference)
//
#include <hip/hip_runtime.h>
#include <hip/hip_bf16.h>

typedef __attribute__((ext_vector_type(8))) short bf16x8;
typedef __attribute__((ext_vector_type(4))) float f32x4;
typedef __attribute__((ext_vector_type(4))) unsigned short u16x4;

#define B_NUM 2048
#define F_NUM 40
#define E_DIM 32
#define P_NUM 780
#define D_DIM 16
#define PC_N  65            // pair chunks (grid.y)
#define PC_SZ 12            // 65*12 = 780 exactly
#define XROW  (F_NUM * E_DIM)   // 1280 floats per batch row
#define LN_EPS 1e-3f

// workspace layout (bytes)
#define CNT_OFF 0           // int cnt[16], zeroed per launch via hipMemsetAsync
#define HP_OFF  256         // hpart f32 [PC_N][B][D] = 8.5 MB

static __device__ __forceinline__ unsigned short f2b(float f) {
  unsigned u = __builtin_bit_cast(unsigned, f);
  u += 0x7fffu + ((u >> 16) & 1u);                 // round-to-nearest-even
  return (unsigned short)(u >> 16);
}
static __device__ __forceinline__ short fcvt(float f) {
  return (short)__bfloat16_as_ushort(__float2bfloat16(f));
}

// convert one 8-float span of an x row to a bf16x8 MFMA fragment
static __device__ __forceinline__ bf16x8 xi_bf(const float* p) {
  float4 a = *reinterpret_cast<const float4*>(p);
  float4 b = *reinterpret_cast<const float4*>(p + 4);
  bf16x8 v;
  v[0] = fcvt(a.x); v[1] = fcvt(a.y); v[2] = fcvt(a.z); v[3] = fcvt(a.w);
  v[4] = fcvt(b.x); v[5] = fcvt(b.y); v[6] = fcvt(b.z); v[7] = fcvt(b.w);
  return v;
}

// ---------------------------------------------------------------------------
// Single fused kernel: in-LDS W-frag prep + dual-MFMA bilinear+dense + last-
// block LayerNorm.
//   MFMA1: t[fo,b] = W_p^T xi ; u = bf16(t * xj) is the B-fragment of MFMA2
//   whose A = dw[p,d] replicated over k: MFMA2 does the f-reduction AND the
//   dense fold, accumulating h[d,b] over 12 pairs in one f32x4 per n-tile.
// grid (16, 65) = 1040 blocks, block 256 = 4 waves (wave = 32 batches).
// LDS 48 KB -> 3 blocks/CU, 12 waves/CU.
__global__ __launch_bounds__(256, 3) void fused_all_kernel(
    const float* __restrict__ x, const float* __restrict__ W,
    const float* __restrict__ dw, const float* __restrict__ db,
    const float* __restrict__ gamma, const float* __restrict__ beta,
    float* __restrict__ out, float* __restrict__ hpart, int* __restrict__ cnt) {
  __shared__ unsigned short wraw[PC_SZ * 1024];                  // 24 KB bf16 W [pl][e][f]
  __shared__ __align__(16) unsigned short afrag[PC_SZ * 2 * 512];// 24 KB a-frags
  __shared__ int isLast;

  const int tid  = threadIdx.x;
  const int lane = tid & 63, wv = tid >> 6;
  const int lhi = lane >> 4, llo = lane & 15;
  const int bbk = blockIdx.x;
  const int bb  = bbk * 128 + wv * 32;
  const int pc  = blockIdx.y;
  const int p0  = pc * PC_SZ;

  // ---- stage this chunk's 12 W matrices (48 KB f32 -> 24 KB bf16) ----
  {
    const float* Wsrc = W + (size_t)p0 * 1024;
#pragma unroll
    for (int it = 0; it < PC_SZ; ++it) {
      const int L = it * 1024 + tid * 4;
      float4 v = *reinterpret_cast<const float4*>(Wsrc + L);
      u16x4 o;
      o[0] = f2b(v.x); o[1] = f2b(v.y); o[2] = f2b(v.z); o[3] = f2b(v.w);
      *reinterpret_cast<u16x4*>(&wraw[L]) = o;                   // ds_write_b64
    }
  }
  __syncthreads();

  // ---- build per-lane A-fragments with f-PERMUTED m-rows ----
  // A-frag (16x16x32): lane l holds A[m=l&15][k=(l>>4)*8+t]; m -> fo =
  // (m>>2)*8+frag*4+(m&3), so C-row m=lhi*4+r maps to fo=lhi*8+frag*4+r:
  // the lane's 8 xj values are the contiguous span f in [lhi*8, lhi*8+8).
#pragma unroll
  for (int s = 0; s < 3; ++s) {
    const int pl = wv * 3 + s;
#pragma unroll
    for (int frag = 0; frag < 2; ++frag) {
      const int fo = (llo >> 2) * 8 + frag * 4 + (llo & 3);
      bf16x8 v;
#pragma unroll
      for (int t = 0; t < 8; ++t)
        v[t] = (short)wraw[pl * 1024 + (lhi * 8 + t) * E_DIM + fo];
      *reinterpret_cast<bf16x8*>(&afrag[(pl * 2 + frag) * 512 + lane * 8]) = v;
    }
  }
  __syncthreads();

  // ---- pair walk (combinations(range(40),2) order) ----
  int ii[PC_SZ], jj[PC_SZ];
  {
    int i = 0;
    while ((i + 1) * (79 - (i + 1)) / 2 <= p0) ++i;
    ii[0] = i; jj[0] = i + 1 + (p0 - i * (79 - i) / 2);
  }
#pragma unroll
  for (int k = 1; k < PC_SZ; ++k) {
    int in_ = ii[k - 1], jn = jj[k - 1] + 1;
    if (jn == F_NUM) { ++in_; jn = in_ + 1; }
    ii[k] = in_; jj[k] = jn;
  }

  const float* xr0 = x + (size_t)(bb + llo) * XROW;    // n-tile 0 row base
  const float* xr1 = xr0 + 16 * XROW;                  // n-tile 1

  bf16x8 bf0 = xi_bf(xr0 + ii[0] * E_DIM + lhi * 8);
  bf16x8 bf1 = xi_bf(xr1 + ii[0] * E_DIM + lhi * 8);
  f32x4 xj0a = *reinterpret_cast<const f32x4*>(xr0 + jj[0] * E_DIM + lhi * 8);
  f32x4 xj0b = *reinterpret_cast<const f32x4*>(xr0 + jj[0] * E_DIM + lhi * 8 + 4);
  f32x4 xj1a = *reinterpret_cast<const f32x4*>(xr1 + jj[0] * E_DIM + lhi * 8);
  f32x4 xj1b = *reinterpret_cast<const f32x4*>(xr1 + jj[0] * E_DIM + lhi * 8 + 4);
  float dwv = dw[p0 * D_DIM + llo];

  f32x4 acc0 = {0.f, 0.f, 0.f, 0.f};
  f32x4 acc1 = {0.f, 0.f, 0.f, 0.f};
  const f32x4 z = {0.f, 0.f, 0.f, 0.f};

#pragma unroll
  for (int k = 0; k < PC_SZ; ++k) {
    // ---- 1-deep prefetch of pair k+1 (issues before the MFMA chain) ----
    f32x4 n0a = xj0a, n0b = xj0b, n1a = xj1a, n1b = xj1b;
    bf16x8 nbf0 = bf0, nbf1 = bf1;
    float ndw = dwv;
    if (k + 1 < PC_SZ) {
      n0a = *reinterpret_cast<const f32x4*>(xr0 + jj[k + 1] * E_DIM + lhi * 8);
      n0b = *reinterpret_cast<const f32x4*>(xr0 + jj[k + 1] * E_DIM + lhi * 8 + 4);
      n1a = *reinterpret_cast<const f32x4*>(xr1 + jj[k + 1] * E_DIM + lhi * 8);
      n1b = *reinterpret_cast<const f32x4*>(xr1 + jj[k + 1] * E_DIM + lhi * 8 + 4);
      ndw = dw[(p0 + k + 1) * D_DIM + llo];
      if (ii[k + 1] != ii[k]) {                        // wave-uniform branch
        nbf0 = xi_bf(xr0 + ii[k + 1] * E_DIM + lhi * 8);
        nbf1 = xi_bf(xr1 + ii[k + 1] * E_DIM + lhi * 8);
      }
    }
    // ---- compute pair k (a-frags from LDS: 2x ds_read_b128) ----
    const bf16x8 a0 = *reinterpret_cast<const bf16x8*>(&afrag[(k * 2 + 0) * 512 + lane * 8]);
    const bf16x8 a1 = *reinterpret_cast<const bf16x8*>(&afrag[(k * 2 + 1) * 512 + lane * 8]);
    const f32x4 c00 = __builtin_amdgcn_mfma_f32_16x16x32_bf16(a0, bf0, z, 0, 0, 0);
    const f32x4 c01 = __builtin_amdgcn_mfma_f32_16x16x32_bf16(a1, bf0, z, 0, 0, 0);
    const f32x4 c10 = __builtin_amdgcn_mfma_f32_16x16x32_bf16(a0, bf1, z, 0, 0, 0);
    const f32x4 c11 = __builtin_amdgcn_mfma_f32_16x16x32_bf16(a1, bf1, z, 0, 0, 0);

    const short dwb = fcvt(dwv);
    bf16x8 a2;
#pragma unroll
    for (int t = 0; t < 8; ++t) a2[t] = dwb;

    bf16x8 u0, u1;                                     // B-frag of MFMA2
#pragma unroll
    for (int t = 0; t < 4; ++t) {
      u0[t]     = fcvt(c00[t] * xj0a[t]);
      u0[t + 4] = fcvt(c01[t] * xj0b[t]);
      u1[t]     = fcvt(c10[t] * xj1a[t]);
      u1[t + 4] = fcvt(c11[t] * xj1b[t]);
    }
    acc0 = __builtin_amdgcn_mfma_f32_16x16x32_bf16(a2, u0, acc0, 0, 0, 0);
    acc1 = __builtin_amdgcn_mfma_f32_16x16x32_bf16(a2, u1, acc1, 0, 0, 0);

    // ---- rotate ----
    xj0a = n0a; xj0b = n0b; xj1a = n1a; xj1b = n1b;
    bf0 = nbf0; bf1 = nbf1; dwv = ndw;
  }

  // C2 layout: lane holds b=llo, d=lhi*4+r -> coalesced float4 stores
  float* hp = hpart + (size_t)pc * B_NUM * D_DIM;
  *reinterpret_cast<f32x4*>(hp + (size_t)(bb + llo) * D_DIM + lhi * 4) = acc0;
  *reinterpret_cast<f32x4*>(hp + (size_t)(bb + 16 + llo) * D_DIM + lhi * 4) = acc1;

  // ---- completion protocol: last block of this batch-stripe does the LN ----
  __threadfence();                                     // release our stores
  __syncthreads();                                     // all threads' fences done
  if (tid == 0) isLast = (atomicAdd(&cnt[bbk], 1) == PC_N - 1);
  __syncthreads();
  if (!isLast) return;

  __threadfence();                                     // acquire
  const int d  = tid & 15;
  const int br = tid >> 4;                             // 0..15
  const float g = gamma[d], be = beta[d], bi = db[d];
#pragma unroll
  for (int q = 0; q < 8; ++q) {
    const int b = bbk * 128 + q * 16 + br;
    float acc = bi;
    const float* hpb = hpart + (size_t)b * D_DIM + d;
    for (int p = 0; p < PC_N; ++p)                     // agent-scope coherent reads
      acc += __hip_atomic_load(hpb + (size_t)p * B_NUM * D_DIM,
                               __ATOMIC_RELAXED, __HIP_MEMORY_SCOPE_AGENT);
    float sum = acc;
    sum += __shfl_xor(sum, 1); sum += __shfl_xor(sum, 2);
    sum += __shfl_xor(sum, 4); sum += __shfl_xor(sum, 8);
    const float mu = sum * (1.f / D_DIM);
    const float dev = acc - mu;
    float v = dev * dev;
    v += __shfl_xor(v, 1); v += __shfl_xor(v, 2);
    v += __shfl_xor(v, 4); v += __shfl_xor(v, 8);
    const float rs = rsqrtf(v * (1.f / D_DIM) + LN_EPS);
    out[(size_t)b * D_DIM + d] = dev * rs * g + be;
  }
}

extern "C" void kernel_launch(void* const* d_in, const int* in_sizes, int n_in,
                              void* d_out, int out_size, void* d_ws, size_t ws_size,
                              hipStream_t stream) {
  const float* x     = (const float*)d_in[0];
  const float* W     = (const float*)d_in[1];
  const float* dw    = (const float*)d_in[2];
  const float* db    = (const float*)d_in[3];
  const float* gamma = (const float*)d_in[4];
  const float* beta  = (const float*)d_in[5];
  float* out = (float*)d_out;

  int*   cnt   = (int*)((char*)d_ws + CNT_OFF);
  float* hpart = (float*)((char*)d_ws + HP_OFF);

  // zero the completion counters every call (graph-capturable stream op)
  hipMemsetAsync(cnt, 0, 256, stream);

  dim3 g(B_NUM / 128, PC_N);
  fused_all_kernel<<<g, 256, 0, stream>>>(x, W, dw, db, gamma, beta,
                                          out, hpart, cnt);
}

// Round 13
// 48.149 us; speedup vs baseline: 3.1621x; 3.1621x over previous
//
#include <hip/hip_runtime.h>
#include <hip/hip_bf16.h>

typedef __attribute__((ext_vector_type(8))) short bf16x8;
typedef __attribute__((ext_vector_type(4))) float f32x4;
typedef __attribute__((ext_vector_type(4))) unsigned short u16x4;

#define B_NUM 2048
#define F_NUM 40
#define E_DIM 32
#define P_NUM 780
#define D_DIM 16
#define PC_N  65            // pair chunks (grid.y)
#define PC_SZ 12            // 65*12 = 780 exactly
#define XROW  (F_NUM * E_DIM)   // 1280 floats per batch row
#define LN_EPS 1e-3f

// workspace layout (bytes)
#define HP_OFF  0           // hpart f32 [PC_N][B][D] = 8.5 MB

static __device__ __forceinline__ unsigned short f2b(float f) {
  unsigned u = __builtin_bit_cast(unsigned, f);
  u += 0x7fffu + ((u >> 16) & 1u);                 // round-to-nearest-even
  return (unsigned short)(u >> 16);
}
static __device__ __forceinline__ short fcvt(float f) {
  return (short)__bfloat16_as_ushort(__float2bfloat16(f));
}

// convert one 8-float span of an x row to a bf16x8 MFMA fragment
static __device__ __forceinline__ bf16x8 xi_bf(const float* p) {
  float4 a = *reinterpret_cast<const float4*>(p);
  float4 b = *reinterpret_cast<const float4*>(p + 4);
  bf16x8 v;
  v[0] = fcvt(a.x); v[1] = fcvt(a.y); v[2] = fcvt(a.z); v[3] = fcvt(a.w);
  v[4] = fcvt(b.x); v[5] = fcvt(b.y); v[6] = fcvt(b.z); v[7] = fcvt(b.w);
  return v;
}

// ---------------------------------------------------------------------------
// Fused kernel (self-contained; no prep launch): in-LDS W-frag build +
// dual-MFMA bilinear+dense.
//   MFMA1: t[fo,b] = W_p^T xi ; u = bf16(t * xj) is the B-fragment of MFMA2
//   whose A = dw[p,d] replicated over k: MFMA2 does the f-reduction AND the
//   dense fold, accumulating h[d,b] over 12 pairs in one f32x4 per n-tile.
// grid (16, 65) = 1040 blocks, block 256 = 4 waves (wave = 32 batches).
// LDS 48 KB -> 3 blocks/CU.
__global__ __launch_bounds__(256, 3) void fused_bilinear_dense_kernel(
    const float* __restrict__ x, const float* __restrict__ W,
    const float* __restrict__ dw, float* __restrict__ hpart) {
  __shared__ unsigned short wraw[PC_SZ * 1024];                  // 24 KB bf16 W [pl][e][f]
  __shared__ __align__(16) unsigned short afrag[PC_SZ * 2 * 512];// 24 KB a-frags

  const int tid  = threadIdx.x;
  const int lane = tid & 63, wv = tid >> 6;
  const int lhi = lane >> 4, llo = lane & 15;
  const int bb  = blockIdx.x * 128 + wv * 32;
  const int pc  = blockIdx.y;
  const int p0  = pc * PC_SZ;

  // ---- stage this chunk's 12 W matrices (48 KB f32 -> 24 KB bf16) ----
  {
    const float* Wsrc = W + (size_t)p0 * 1024;
#pragma unroll
    for (int it = 0; it < PC_SZ; ++it) {
      const int L = it * 1024 + tid * 4;
      float4 v = *reinterpret_cast<const float4*>(Wsrc + L);
      u16x4 o;
      o[0] = f2b(v.x); o[1] = f2b(v.y); o[2] = f2b(v.z); o[3] = f2b(v.w);
      *reinterpret_cast<u16x4*>(&wraw[L]) = o;                   // ds_write_b64
    }
  }
  __syncthreads();

  // ---- build per-lane A-fragments with f-PERMUTED m-rows ----
  // A-frag (16x16x32): lane l holds A[m=l&15][k=(l>>4)*8+t]; m -> fo =
  // (m>>2)*8+frag*4+(m&3), so C-row m=lhi*4+r maps to fo=lhi*8+frag*4+r:
  // the lane's 8 xj values are the contiguous span f in [lhi*8, lhi*8+8).
#pragma unroll
  for (int s = 0; s < 3; ++s) {
    const int pl = wv * 3 + s;
#pragma unroll
    for (int frag = 0; frag < 2; ++frag) {
      const int fo = (llo >> 2) * 8 + frag * 4 + (llo & 3);
      bf16x8 v;
#pragma unroll
      for (int t = 0; t < 8; ++t)
        v[t] = (short)wraw[pl * 1024 + (lhi * 8 + t) * E_DIM + fo];
      *reinterpret_cast<bf16x8*>(&afrag[(pl * 2 + frag) * 512 + lane * 8]) = v;
    }
  }
  __syncthreads();

  // ---- pair walk (combinations(range(40),2) order) ----
  int ii[PC_SZ], jj[PC_SZ];
  {
    int i = 0;
    while ((i + 1) * (79 - (i + 1)) / 2 <= p0) ++i;
    ii[0] = i; jj[0] = i + 1 + (p0 - i * (79 - i) / 2);
  }
#pragma unroll
  for (int k = 1; k < PC_SZ; ++k) {
    int in_ = ii[k - 1], jn = jj[k - 1] + 1;
    if (jn == F_NUM) { ++in_; jn = in_ + 1; }
    ii[k] = in_; jj[k] = jn;
  }

  const float* xr0 = x + (size_t)(bb + llo) * XROW;    // n-tile 0 row base
  const float* xr1 = xr0 + 16 * XROW;                  // n-tile 1

  bf16x8 bf0 = xi_bf(xr0 + ii[0] * E_DIM + lhi * 8);
  bf16x8 bf1 = xi_bf(xr1 + ii[0] * E_DIM + lhi * 8);
  f32x4 xj0a = *reinterpret_cast<const f32x4*>(xr0 + jj[0] * E_DIM + lhi * 8);
  f32x4 xj0b = *reinterpret_cast<const f32x4*>(xr0 + jj[0] * E_DIM + lhi * 8 + 4);
  f32x4 xj1a = *reinterpret_cast<const f32x4*>(xr1 + jj[0] * E_DIM + lhi * 8);
  f32x4 xj1b = *reinterpret_cast<const f32x4*>(xr1 + jj[0] * E_DIM + lhi * 8 + 4);
  float dwv = dw[p0 * D_DIM + llo];

  f32x4 acc0 = {0.f, 0.f, 0.f, 0.f};
  f32x4 acc1 = {0.f, 0.f, 0.f, 0.f};
  const f32x4 z = {0.f, 0.f, 0.f, 0.f};

#pragma unroll
  for (int k = 0; k < PC_SZ; ++k) {
    // ---- 1-deep prefetch of pair k+1 (issues before the MFMA chain) ----
    f32x4 n0a = xj0a, n0b = xj0b, n1a = xj1a, n1b = xj1b;
    bf16x8 nbf0 = bf0, nbf1 = bf1;
    float ndw = dwv;
    if (k + 1 < PC_SZ) {
      n0a = *reinterpret_cast<const f32x4*>(xr0 + jj[k + 1] * E_DIM + lhi * 8);
      n0b = *reinterpret_cast<const f32x4*>(xr0 + jj[k + 1] * E_DIM + lhi * 8 + 4);
      n1a = *reinterpret_cast<const f32x4*>(xr1 + jj[k + 1] * E_DIM + lhi * 8);
      n1b = *reinterpret_cast<const f32x4*>(xr1 + jj[k + 1] * E_DIM + lhi * 8 + 4);
      ndw = dw[(p0 + k + 1) * D_DIM + llo];
      if (ii[k + 1] != ii[k]) {                        // wave-uniform branch
        nbf0 = xi_bf(xr0 + ii[k + 1] * E_DIM + lhi * 8);
        nbf1 = xi_bf(xr1 + ii[k + 1] * E_DIM + lhi * 8);
      }
    }
    // ---- compute pair k (a-frags from LDS: 2x ds_read_b128) ----
    const bf16x8 a0 = *reinterpret_cast<const bf16x8*>(&afrag[(k * 2 + 0) * 512 + lane * 8]);
    const bf16x8 a1 = *reinterpret_cast<const bf16x8*>(&afrag[(k * 2 + 1) * 512 + lane * 8]);
    const f32x4 c00 = __builtin_amdgcn_mfma_f32_16x16x32_bf16(a0, bf0, z, 0, 0, 0);
    const f32x4 c01 = __builtin_amdgcn_mfma_f32_16x16x32_bf16(a1, bf0, z, 0, 0, 0);
    const f32x4 c10 = __builtin_amdgcn_mfma_f32_16x16x32_bf16(a0, bf1, z, 0, 0, 0);
    const f32x4 c11 = __builtin_amdgcn_mfma_f32_16x16x32_bf16(a1, bf1, z, 0, 0, 0);

    const short dwb = fcvt(dwv);
    bf16x8 a2;
#pragma unroll
    for (int t = 0; t < 8; ++t) a2[t] = dwb;

    bf16x8 u0, u1;                                     // B-frag of MFMA2
#pragma unroll
    for (int t = 0; t < 4; ++t) {
      u0[t]     = fcvt(c00[t] * xj0a[t]);
      u0[t + 4] = fcvt(c01[t] * xj0b[t]);
      u1[t]     = fcvt(c10[t] * xj1a[t]);
      u1[t + 4] = fcvt(c11[t] * xj1b[t]);
    }
    acc0 = __builtin_amdgcn_mfma_f32_16x16x32_bf16(a2, u0, acc0, 0, 0, 0);
    acc1 = __builtin_amdgcn_mfma_f32_16x16x32_bf16(a2, u1, acc1, 0, 0, 0);

    // ---- rotate ----
    xj0a = n0a; xj0b = n0b; xj1a = n1a; xj1b = n1b;
    bf0 = nbf0; bf1 = nbf1; dwv = ndw;
  }

  // C2 layout: lane holds b=llo, d=lhi*4+r -> coalesced float4 stores
  float* hp = hpart + (size_t)pc * B_NUM * D_DIM;
  *reinterpret_cast<f32x4*>(hp + (size_t)(bb + llo) * D_DIM + lhi * 4) = acc0;
  *reinterpret_cast<f32x4*>(hp + (size_t)(bb + 16 + llo) * D_DIM + lhi * 4) = acc1;
}

// ---------------------------------------------------------------------------
// Final: sum 65 h-partials + bias, LayerNorm. grid 256, block 128 (8 b each)
// -> one block per CU; thread = (b, d), coalesced 512 B/block/iter.
__global__ __launch_bounds__(128) void reduce_ln_kernel(
    const float* __restrict__ hpart, const float* __restrict__ bias,
    const float* __restrict__ gamma, const float* __restrict__ beta,
    float* __restrict__ out) {
  const int t = threadIdx.x;
  const int d = t & 15;
  const int b = blockIdx.x * 8 + (t >> 4);
  float acc = bias[d];
  const float* hp = hpart + (size_t)b * D_DIM + d;
#pragma unroll 5
  for (int pc = 0; pc < PC_N; ++pc)
    acc += hp[(size_t)pc * B_NUM * D_DIM];

  float sum = acc;
  sum += __shfl_xor(sum, 1); sum += __shfl_xor(sum, 2);
  sum += __shfl_xor(sum, 4); sum += __shfl_xor(sum, 8);
  const float mu = sum * (1.f / D_DIM);
  const float dev = acc - mu;
  float v = dev * dev;
  v += __shfl_xor(v, 1); v += __shfl_xor(v, 2);
  v += __shfl_xor(v, 4); v += __shfl_xor(v, 8);
  const float rs = rsqrtf(v * (1.f / D_DIM) + LN_EPS);
  out[(size_t)b * D_DIM + d] = dev * rs * gamma[d] + beta[d];
}

extern "C" void kernel_launch(void* const* d_in, const int* in_sizes, int n_in,
                              void* d_out, int out_size, void* d_ws, size_t ws_size,
                              hipStream_t stream) {
  const float* x     = (const float*)d_in[0];
  const float* W     = (const float*)d_in[1];
  const float* dw    = (const float*)d_in[2];
  const float* db    = (const float*)d_in[3];
  const float* gamma = (const float*)d_in[4];
  const float* beta  = (const float*)d_in[5];
  float* out = (float*)d_out;

  float* hpart = (float*)((char*)d_ws + HP_OFF);

  dim3 g(B_NUM / 128, PC_N);
  fused_bilinear_dense_kernel<<<g, 256, 0, stream>>>(x, W, dw, hpart);

  reduce_ln_kernel<<<B_NUM / 8, 128, 0, stream>>>(hpart, db, gamma, beta, out);
}

// Round 15
// 34.288 us; speedup vs baseline: 4.4403x; 1.4042x over previous
//
#include <hip/hip_runtime.h>
#include <hip/hip_bf16.h>

typedef __attribute__((ext_vector_type(8))) short bf16x8;
typedef __attribute__((ext_vector_type(4))) float f32x4;

#define B_NUM 2048
#define F_NUM 40
#define E_DIM 32
#define P_NUM 780
#define D_DIM 16
#define PC_N  65            // pair chunks
#define PC_SZ 12            // 65*12 = 780 exactly
#define LN_EPS 1e-3f

// workspace layout (bytes)
#define WF_OFF 0
#define WF_BYTES (P_NUM * 2 * 64 * 8 * 2)          // 1.6 MB W fragments
#define XB_OFF  WF_BYTES
#define XB_BYTES (F_NUM * 4 * B_NUM * 8 * 2)       // 5.2 MB packed bf16 x [f][e8][b][8]
#define DW_OFF  (XB_OFF + XB_BYTES)
#define DW_BYTES 32768                             // bf16 dense_w
#define HP_OFF  (DW_OFF + DW_BYTES)                // hpart 65*2048*16*4 = 8.5 MB

static __device__ __forceinline__ unsigned short f2b(float f) {
  unsigned u = __builtin_bit_cast(unsigned, f);
  u += 0x7fffu + ((u >> 16) & 1u);                 // round-to-nearest-even
  return (unsigned short)(u >> 16);
}
static __device__ __forceinline__ short f2bs(float f) { return (short)f2b(f); }
static __device__ __forceinline__ short fcvt(float f) {
  return (short)__bfloat16_as_ushort(__float2bfloat16(f));
}
static __device__ __forceinline__ float b2f(unsigned short u) {
  return __builtin_bit_cast(float, (unsigned)u << 16);
}

// ---------------------------------------------------------------------------
// Prep (identical to the proven R9 kernel):
//  blocks [0,640): x -> packed bf16 [f][e8][b][8] (b-minor: coalesced writes).
//  blocks [640,835): W -> per-lane A-fragments, f-permuted rows
//    (m -> fo=(m>>2)*8+frag*4+(m&3)), via LDS transpose. One pair per wave.
//  block 835: dense_w -> bf16 table.
__global__ __launch_bounds__(256) void prep_kernel(
    const float* __restrict__ x, const float* __restrict__ W,
    const float* __restrict__ dw, short* __restrict__ xbp,
    short* __restrict__ wfrag, unsigned short* __restrict__ dwbf) {
  const int lane = threadIdx.x & 63;
  const int wv   = threadIdx.x >> 6;
  const int lhi = lane >> 4, llo = lane & 15;
  __shared__ float wst[4][E_DIM * E_DIM];          // 16 KB, one W_p per wave

  if (blockIdx.x < 640) {
    const int u  = blockIdx.x * 256 + threadIdx.x;
    const int b  = u & (B_NUM - 1);
    const int fp = u >> 11;                        // 0..79: (f, e16-half)
    const int f  = fp >> 1;
    const float* src = x + ((size_t)b * F_NUM + f) * E_DIM + (fp & 1) * 16;
    const float4 v0 = *reinterpret_cast<const float4*>(src);
    const float4 v1 = *reinterpret_cast<const float4*>(src + 4);
    const float4 v2 = *reinterpret_cast<const float4*>(src + 8);
    const float4 v3 = *reinterpret_cast<const float4*>(src + 12);
    const int plane = f * 4 + (fp & 1) * 2;        // e8 plane index
    bf16x8 o0, o1;
    o0[0] = f2bs(v0.x); o0[1] = f2bs(v0.y); o0[2] = f2bs(v0.z); o0[3] = f2bs(v0.w);
    o0[4] = f2bs(v1.x); o0[5] = f2bs(v1.y); o0[6] = f2bs(v1.z); o0[7] = f2bs(v1.w);
    o1[0] = f2bs(v2.x); o1[1] = f2bs(v2.y); o1[2] = f2bs(v2.z); o1[3] = f2bs(v2.w);
    o1[4] = f2bs(v3.x); o1[5] = f2bs(v3.y); o1[6] = f2bs(v3.z); o1[7] = f2bs(v3.w);
    *reinterpret_cast<bf16x8*>(xbp + ((size_t)plane * B_NUM + b) * 8)       = o0;
    *reinterpret_cast<bf16x8*>(xbp + ((size_t)(plane + 1) * B_NUM + b) * 8) = o1;
  } else if (blockIdx.x < 640 + 195) {
    const int p = (blockIdx.x - 640) * 4 + wv;
    const float* Wp = W + (size_t)p * (E_DIM * E_DIM);
#pragma unroll
    for (int k = 0; k < 4; ++k) {
      float4 v = *reinterpret_cast<const float4*>(Wp + k * 256 + lane * 4);
      *reinterpret_cast<float4*>(&wst[wv][k * 256 + lane * 4]) = v;
    }
    // same-wave LDS RAW: compiler inserts lgkmcnt wait; no barrier needed
#pragma unroll
    for (int frag = 0; frag < 2; ++frag) {
      const int fo = (llo >> 2) * 8 + frag * 4 + (llo & 3);   // permuted f
      bf16x8 v;
#pragma unroll
      for (int t = 0; t < 8; ++t)
        v[t] = f2bs(wst[wv][(lhi * 8 + t) * E_DIM + fo]);     // A[m][k]=W[e=k][fo]
      *reinterpret_cast<bf16x8*>(wfrag + ((size_t)(p * 2 + frag) * 64 + lane) * 8) = v;
    }
  } else {
    for (int t = threadIdx.x; t < P_NUM * D_DIM; t += 256) dwbf[t] = f2b(dw[t]);
  }
}

// ---------------------------------------------------------------------------
// Fused dual-MFMA, 4 n-tiles per wave (64 batches): a0/a1/dw reused across
// 4 B-fragments -> 12 MFMA per {2 a-frag + 4 xj} load set; wave-iteration
// count halved vs the 2-n-tile version.
// MFMA1: t[fo,b] = W_p^T xi ; u = bf16(t * xj) is the B-fragment of MFMA2
// whose A = dw[p,d] replicated over k: MFMA2 does the f-reduction AND the
// dense fold, accumulating h[d,b] in one f32x4 per n-tile.
// grid (8, 65) = 520 blocks, block 256 = 4 waves.
__global__ __launch_bounds__(256, 4) void fused_bilinear_dense_kernel(
    const short* __restrict__ xbp, const short* __restrict__ wfrag,
    const unsigned short* __restrict__ dwbf, float* __restrict__ hpart) {
  const int lane = threadIdx.x & 63;
  const int wv   = threadIdx.x >> 6;
  const int lhi = lane >> 4, llo = lane & 15;
  const int bb = blockIdx.x * 256 + wv * 64;
  const int pc = blockIdx.y;
  const int p0 = pc * PC_SZ;

  int off[4];                                      // packed-table lane offsets
#pragma unroll
  for (int nt = 0; nt < 4; ++nt)
    off[nt] = (lhi * B_NUM + bb + nt * 16 + llo) * 8;
#define XB8(f, o) (*reinterpret_cast<const bf16x8*>(xbp + (size_t)(f) * 65536 + (o)))
#define AFR(p, fr) (*reinterpret_cast<const bf16x8*>( \
    wfrag + ((size_t)((p) * 2 + (fr)) * 64 + lane) * 8))

  // pair walk (combinations(range(40),2) order)
  int ii[PC_SZ], jj[PC_SZ];
  {
    int i = 0;
    while ((i + 1) * (79 - (i + 1)) / 2 <= p0) ++i;
    ii[0] = i; jj[0] = i + 1 + (p0 - i * (79 - i) / 2);
  }
#pragma unroll
  for (int k = 1; k < PC_SZ; ++k) {
    int in_ = ii[k - 1], jn = jj[k - 1] + 1;
    if (jn == F_NUM) { ++in_; jn = in_ + 1; }
    ii[k] = in_; jj[k] = jn;
  }

  bf16x8 bf[4], xj[4];
#pragma unroll
  for (int nt = 0; nt < 4; ++nt) {
    bf[nt] = XB8(ii[0], off[nt]);
    xj[nt] = XB8(jj[0], off[nt]);
  }
  bf16x8 a0 = AFR(p0, 0), a1 = AFR(p0, 1);
  unsigned short dwb = dwbf[p0 * D_DIM + llo];

  f32x4 acc[4];
#pragma unroll
  for (int nt = 0; nt < 4; ++nt) acc[nt] = {0.f, 0.f, 0.f, 0.f};
  const f32x4 z = {0.f, 0.f, 0.f, 0.f};

#pragma unroll
  for (int k = 0; k < PC_SZ; ++k) {
    // ---- 1-deep prefetch of pair k+1 (xj / a-frags / dw only) ----
    bf16x8 nxj[4];
    bf16x8 na0 = a0, na1 = a1;
    unsigned short ndw = dwb;
#pragma unroll
    for (int nt = 0; nt < 4; ++nt) nxj[nt] = xj[nt];
    if (k + 1 < PC_SZ) {
#pragma unroll
      for (int nt = 0; nt < 4; ++nt) nxj[nt] = XB8(jj[k + 1], off[nt]);
      na0 = AFR(p0 + k + 1, 0);
      na1 = AFR(p0 + k + 1, 1);
      ndw = dwbf[(p0 + k + 1) * D_DIM + llo];
    }

    // ---- compute pair k: 8 MFMA1 sharing a0/a1 across 4 B-frags ----
    f32x4 c0[4], c1[4];
#pragma unroll
    for (int nt = 0; nt < 4; ++nt) {
      c0[nt] = __builtin_amdgcn_mfma_f32_16x16x32_bf16(a0, bf[nt], z, 0, 0, 0);
      c1[nt] = __builtin_amdgcn_mfma_f32_16x16x32_bf16(a1, bf[nt], z, 0, 0, 0);
    }

    bf16x8 a2;
#pragma unroll
    for (int t = 0; t < 8; ++t) a2[t] = (short)dwb;

#pragma unroll
    for (int nt = 0; nt < 4; ++nt) {
      bf16x8 u;                                    // B-frag of MFMA2
#pragma unroll
      for (int t = 0; t < 4; ++t) {
        u[t]     = fcvt(c0[nt][t] * b2f((unsigned short)xj[nt][t]));
        u[t + 4] = fcvt(c1[nt][t] * b2f((unsigned short)xj[nt][t + 4]));
      }
      acc[nt] = __builtin_amdgcn_mfma_f32_16x16x32_bf16(a2, u, acc[nt], 0, 0, 0);
    }

    // ---- rotate; xi reload only on (rare) i-change, not prefetched ----
#pragma unroll
    for (int nt = 0; nt < 4; ++nt) xj[nt] = nxj[nt];
    a0 = na0; a1 = na1; dwb = ndw;
    if (k + 1 < PC_SZ && ii[k + 1] != ii[k]) {     // wave-uniform branch
#pragma unroll
      for (int nt = 0; nt < 4; ++nt) bf[nt] = XB8(ii[k + 1], off[nt]);
    }
  }
#undef XB8
#undef AFR

  // C2 layout: lane holds b=llo, d=lhi*4+r -> coalesced float4 stores
  float* hp = hpart + (size_t)pc * B_NUM * D_DIM;
#pragma unroll
  for (int nt = 0; nt < 4; ++nt)
    *reinterpret_cast<f32x4*>(hp + (size_t)(bb + nt * 16 + llo) * D_DIM + lhi * 4) = acc[nt];
}

// ---------------------------------------------------------------------------
// Final: sum 65 h-partials + bias, LayerNorm. grid 128, block 256;
// thread = (b, d): per-pc the block reads 1 KB contiguous.
__global__ __launch_bounds__(256) void reduce_ln_kernel(
    const float* __restrict__ hpart, const float* __restrict__ bias,
    const float* __restrict__ gamma, const float* __restrict__ beta,
    float* __restrict__ out) {
  const int t = threadIdx.x;
  const int d = t & 15;
  const int b = blockIdx.x * 16 + (t >> 4);
  float acc = bias[d];
  const float* hp = hpart + (size_t)b * D_DIM + d;
#pragma unroll 5
  for (int pc = 0; pc < PC_N; ++pc)
    acc += hp[(size_t)pc * B_NUM * D_DIM];

  float sum = acc;
  sum += __shfl_xor(sum, 1); sum += __shfl_xor(sum, 2);
  sum += __shfl_xor(sum, 4); sum += __shfl_xor(sum, 8);
  const float mu = sum * (1.f / D_DIM);
  const float dev = acc - mu;
  float v = dev * dev;
  v += __shfl_xor(v, 1); v += __shfl_xor(v, 2);
  v += __shfl_xor(v, 4); v += __shfl_xor(v, 8);
  const float rs = rsqrtf(v * (1.f / D_DIM) + LN_EPS);
  out[(size_t)b * D_DIM + d] = dev * rs * gamma[d] + beta[d];
}

extern "C" void kernel_launch(void* const* d_in, const int* in_sizes, int n_in,
                              void* d_out, int out_size, void* d_ws, size_t ws_size,
                              hipStream_t stream) {
  const float* x     = (const float*)d_in[0];
  const float* W     = (const float*)d_in[1];
  const float* dw    = (const float*)d_in[2];
  const float* db    = (const float*)d_in[3];
  const float* gamma = (const float*)d_in[4];
  const float* beta  = (const float*)d_in[5];
  float* out = (float*)d_out;

  short*          wfrag = (short*)((char*)d_ws + WF_OFF);
  short*          xbp   = (short*)((char*)d_ws + XB_OFF);
  unsigned short* dwbf  = (unsigned short*)((char*)d_ws + DW_OFF);
  float*          hpart = (float*)((char*)d_ws + HP_OFF);

  prep_kernel<<<640 + 195 + 1, 256, 0, stream>>>(x, W, dw, xbp, wfrag, dwbf);

  dim3 gA(B_NUM / 256, PC_N);
  fused_bilinear_dense_kernel<<<gA, 256, 0, stream>>>(xbp, wfrag, dwbf, hpart);

  reduce_ln_kernel<<<B_NUM / 16, 256, 0, stream>>>(hpart, db, gamma, beta, out);
}